// Round 1
// baseline (7219.085 us; speedup 1.0000x reference)
//
#include <hip/hip_runtime.h>

// LightGCN layer on MI355X.
// Inputs:
//   d_in[0] u_emb    : float32 [100000, 64]
//   d_in[1] i_emb    : float32 [50000, 64]
//   d_in[2] edge_idx : int32   [2, 4000000]  (row 0 = user_idx, row 1 = item_idx)
//   d_in[3] weights  : float32 [4000000]
// Output (concat): new_u_emb [100000,64] then new_i_emb [50000,64], float32.
// Workspace: user_deg (100000 f32) + item_deg (50000 f32).

#define NUSERS 100000
#define NITEMS 50000
#define EDIM 64
#define NEDGES 4000000

__global__ void lgcn_degree_kernel(const int* __restrict__ uidx,
                                   const int* __restrict__ iidx,
                                   float* __restrict__ udeg,
                                   float* __restrict__ ideg) {
    int stride = gridDim.x * blockDim.x;
    for (int e = blockIdx.x * blockDim.x + threadIdx.x; e < NEDGES; e += stride) {
        atomicAdd(&udeg[uidx[e]], 1.0f);
        atomicAdd(&ideg[iidx[e]], 1.0f);
    }
}

// 16 lanes per edge; lane j handles floats [4j, 4j+4) of the 64-dim embedding.
__global__ void lgcn_scatter_kernel(const float* __restrict__ u_emb,
                                    const float* __restrict__ i_emb,
                                    const int* __restrict__ uidx,
                                    const int* __restrict__ iidx,
                                    const float* __restrict__ w,
                                    const float* __restrict__ udeg,
                                    const float* __restrict__ ideg,
                                    float* __restrict__ out_u,
                                    float* __restrict__ out_i) {
    long long t = (long long)blockIdx.x * blockDim.x + threadIdx.x;
    int e    = (int)(t >> 4);
    int lane = (int)(t & 15);
    if (e >= NEDGES) return;

    int u  = uidx[e];
    int it = iidx[e];
    float du = fmaxf(udeg[u], 1.0f);
    float di = fmaxf(ideg[it], 1.0f);
    float ew = w[e] * rsqrtf(du * di);

    const float4 iv = *reinterpret_cast<const float4*>(i_emb + (size_t)it * EDIM + lane * 4);
    const float4 uv = *reinterpret_cast<const float4*>(u_emb + (size_t)u  * EDIM + lane * 4);

    float* pu = out_u + (size_t)u  * EDIM + lane * 4;
    float* pi = out_i + (size_t)it * EDIM + lane * 4;

    atomicAdd(pu + 0, iv.x * ew);
    atomicAdd(pu + 1, iv.y * ew);
    atomicAdd(pu + 2, iv.z * ew);
    atomicAdd(pu + 3, iv.w * ew);

    atomicAdd(pi + 0, uv.x * ew);
    atomicAdd(pi + 1, uv.y * ew);
    atomicAdd(pi + 2, uv.z * ew);
    atomicAdd(pi + 3, uv.w * ew);
}

extern "C" void kernel_launch(void* const* d_in, const int* in_sizes, int n_in,
                              void* d_out, int out_size, void* d_ws, size_t ws_size,
                              hipStream_t stream) {
    const float* u_emb = (const float*)d_in[0];
    const float* i_emb = (const float*)d_in[1];
    const int*   eidx  = (const int*)d_in[2];
    const float* w     = (const float*)d_in[3];

    const int* uidx = eidx;            // first NEDGES
    const int* iidx = eidx + NEDGES;   // second NEDGES

    float* udeg = (float*)d_ws;
    float* ideg = udeg + NUSERS;

    float* out_u = (float*)d_out;
    float* out_i = out_u + (size_t)NUSERS * EDIM;

    // Zero degree scratch and outputs (harness poisons them with 0xAA).
    hipMemsetAsync(d_ws, 0, (size_t)(NUSERS + NITEMS) * sizeof(float), stream);
    hipMemsetAsync(d_out, 0, (size_t)out_size * sizeof(float), stream);

    // Degree pass: grid-stride, cap grid at 2048 blocks.
    {
        dim3 block(256);
        int blocks = (NEDGES + 255) / 256;
        if (blocks > 2048) blocks = 2048;
        lgcn_degree_kernel<<<blocks, block, 0, stream>>>(uidx, iidx, udeg, ideg);
    }

    // Scatter pass: 16 threads per edge.
    {
        dim3 block(256);
        long long total_threads = (long long)NEDGES * 16;
        long long blocks = (total_threads + 255) / 256;
        lgcn_scatter_kernel<<<(int)blocks, block, 0, stream>>>(
            u_emb, i_emb, uidx, iidx, w, udeg, ideg, out_u, out_i);
    }
}

// Round 6
// 1282.703 us; speedup vs baseline: 5.6280x; 5.6280x over previous
//
#include <hip/hip_runtime.h>

// LightGCN layer on MI355X — CSR-gather formulation (no f32 scatter atomics).
// Inputs:
//   d_in[0] u_emb    : float32 [100000, 64]
//   d_in[1] i_emb    : float32 [50000, 64]
//   d_in[2] edge_idx : int32   [2, 4000000]  (row 0 = user_idx, row 1 = item_idx)
//   d_in[3] weights  : float32 [4000000]
// Output (concat): new_u_emb [100000,64] then new_i_emb [50000,64], float32.

#define NUSERS 100000
#define NITEMS 50000
#define EDIM 64
#define NEDGES 4000000

// ---------- Pass A: integer degree counts ----------
__global__ void degree_kernel(const int* __restrict__ uidx,
                              const int* __restrict__ iidx,
                              int* __restrict__ udeg,
                              int* __restrict__ ideg) {
    int stride = gridDim.x * blockDim.x;
    for (int e = blockIdx.x * blockDim.x + threadIdx.x; e < NEDGES; e += stride) {
        atomicAdd(&udeg[uidx[e]], 1);
        atomicAdd(&ideg[iidx[e]], 1);
    }
}

// ---------- Pass B: exclusive prefix scan (block 0: users, block 1: items) ----------
__global__ void scan_kernel(const int* __restrict__ udeg,
                            const int* __restrict__ ideg,
                            int* __restrict__ u_off, int* __restrict__ i_off,
                            int* __restrict__ u_cur, int* __restrict__ i_cur) {
    __shared__ int partial[1024];
    const int* cnt; int n; int* off; int* cur;
    if (blockIdx.x == 0) { cnt = udeg; n = NUSERS; off = u_off; cur = u_cur; }
    else                 { cnt = ideg; n = NITEMS; off = i_off; cur = i_cur; }

    int tid = threadIdx.x;
    int chunk = (n + 1023) >> 10;
    int s = tid * chunk;
    int e = min(s + chunk, n);

    int sum = 0;
    for (int i = s; i < e; ++i) sum += cnt[i];
    partial[tid] = sum;
    __syncthreads();

    // Hillis-Steele inclusive scan over 1024 partials.
    for (int d = 1; d < 1024; d <<= 1) {
        int v = partial[tid];
        int add = (tid >= d) ? partial[tid - d] : 0;
        __syncthreads();
        partial[tid] = v + add;
        __syncthreads();
    }

    int run = partial[tid] - sum;  // exclusive base for this thread's chunk
    for (int i = s; i < e; ++i) {
        off[i] = run;
        cur[i] = run;
        run += cnt[i];
    }
}

// ---------- Pass C: build CSR edge records {src_index, edge_weight} ----------
__global__ void build_kernel(const int* __restrict__ uidx,
                             const int* __restrict__ iidx,
                             const float* __restrict__ w,
                             const int* __restrict__ udeg,
                             const int* __restrict__ ideg,
                             int* __restrict__ u_cur, int* __restrict__ i_cur,
                             int2* __restrict__ u_edges, int2* __restrict__ i_edges) {
    int stride = gridDim.x * blockDim.x;
    for (int e = blockIdx.x * blockDim.x + threadIdx.x; e < NEDGES; e += stride) {
        int u  = uidx[e];
        int it = iidx[e];
        float du = (float)max(udeg[u], 1);
        float di = (float)max(ideg[it], 1);
        float ew = w[e] * rsqrtf(du * di);
        int ewb = __float_as_int(ew);
        int pu = atomicAdd(&u_cur[u], 1);
        u_edges[pu] = make_int2(it, ewb);
        int pi = atomicAdd(&i_cur[it], 1);
        i_edges[pi] = make_int2(u, ewb);
    }
}

// ---------- Pass D: gather. 16 lanes per output row, lane j owns floats [4j,4j+4). ----------
__global__ void gather_kernel(const int2* __restrict__ edges,
                              const int* __restrict__ off,
                              const int* __restrict__ deg,
                              const float* __restrict__ src_emb,
                              float* __restrict__ out, int nrows) {
    int t = blockIdx.x * blockDim.x + threadIdx.x;
    int row  = t >> 4;
    int lane = t & 15;
    if (row >= nrows) return;

    int s = off[row];
    int n = deg[row];
    float4 acc = make_float4(0.f, 0.f, 0.f, 0.f);
    for (int k = 0; k < n; ++k) {
        int2 rec = edges[s + k];                       // broadcast within 16-lane group
        float ew = __int_as_float(rec.y);
        const float4 v = *reinterpret_cast<const float4*>(
            src_emb + (size_t)rec.x * EDIM + lane * 4); // coalesced 256B row gather
        acc.x += v.x * ew;
        acc.y += v.y * ew;
        acc.z += v.z * ew;
        acc.w += v.w * ew;
    }
    *reinterpret_cast<float4*>(out + (size_t)row * EDIM + lane * 4) = acc;
}

// ---------- Fallback (ws too small): round-1 atomic scatter ----------
__global__ void fb_degree_kernel(const int* __restrict__ uidx,
                                 const int* __restrict__ iidx,
                                 float* __restrict__ udeg,
                                 float* __restrict__ ideg) {
    int stride = gridDim.x * blockDim.x;
    for (int e = blockIdx.x * blockDim.x + threadIdx.x; e < NEDGES; e += stride) {
        atomicAdd(&udeg[uidx[e]], 1.0f);
        atomicAdd(&ideg[iidx[e]], 1.0f);
    }
}

__global__ void fb_scatter_kernel(const float* __restrict__ u_emb,
                                  const float* __restrict__ i_emb,
                                  const int* __restrict__ uidx,
                                  const int* __restrict__ iidx,
                                  const float* __restrict__ w,
                                  const float* __restrict__ udeg,
                                  const float* __restrict__ ideg,
                                  float* __restrict__ out_u,
                                  float* __restrict__ out_i) {
    long long t = (long long)blockIdx.x * blockDim.x + threadIdx.x;
    int e    = (int)(t >> 4);
    int lane = (int)(t & 15);
    if (e >= NEDGES) return;
    int u  = uidx[e];
    int it = iidx[e];
    float ew = w[e] * rsqrtf(fmaxf(udeg[u], 1.0f) * fmaxf(ideg[it], 1.0f));
    const float4 iv = *reinterpret_cast<const float4*>(i_emb + (size_t)it * EDIM + lane * 4);
    const float4 uv = *reinterpret_cast<const float4*>(u_emb + (size_t)u  * EDIM + lane * 4);
    float* pu = out_u + (size_t)u  * EDIM + lane * 4;
    float* pi = out_i + (size_t)it * EDIM + lane * 4;
    atomicAdd(pu + 0, iv.x * ew); atomicAdd(pu + 1, iv.y * ew);
    atomicAdd(pu + 2, iv.z * ew); atomicAdd(pu + 3, iv.w * ew);
    atomicAdd(pi + 0, uv.x * ew); atomicAdd(pi + 1, uv.y * ew);
    atomicAdd(pi + 2, uv.z * ew); atomicAdd(pi + 3, uv.w * ew);
}

extern "C" void kernel_launch(void* const* d_in, const int* in_sizes, int n_in,
                              void* d_out, int out_size, void* d_ws, size_t ws_size,
                              hipStream_t stream) {
    const float* u_emb = (const float*)d_in[0];
    const float* i_emb = (const float*)d_in[1];
    const int*   eidx  = (const int*)d_in[2];
    const float* w     = (const float*)d_in[3];

    const int* uidx = eidx;
    const int* iidx = eidx + NEDGES;

    float* out_u = (float*)d_out;
    float* out_i = out_u + (size_t)NUSERS * EDIM;

    // Workspace layout (8B-aligned first):
    //   u_edges [NEDGES int2] | i_edges [NEDGES int2] |
    //   udeg, ideg, u_off, i_off, u_cur, i_cur (ints)
    size_t need = (size_t)NEDGES * 8 * 2 + (size_t)(NUSERS + NITEMS) * 4 * 3;

    if (ws_size >= need) {
        char* p = (char*)d_ws;
        int2* u_edges = (int2*)p;                 p += (size_t)NEDGES * 8;
        int2* i_edges = (int2*)p;                 p += (size_t)NEDGES * 8;
        int* udeg = (int*)p;                      p += (size_t)NUSERS * 4;
        int* ideg = (int*)p;                      p += (size_t)NITEMS * 4;
        int* u_off = (int*)p;                     p += (size_t)NUSERS * 4;
        int* i_off = (int*)p;                     p += (size_t)NITEMS * 4;
        int* u_cur = (int*)p;                     p += (size_t)NUSERS * 4;
        int* i_cur = (int*)p;

        // zero only the degree counters (contiguous region)
        hipMemsetAsync(udeg, 0, (size_t)(NUSERS + NITEMS) * 4, stream);

        degree_kernel<<<2048, 256, 0, stream>>>(uidx, iidx, udeg, ideg);
        scan_kernel<<<2, 1024, 0, stream>>>(udeg, ideg, u_off, i_off, u_cur, i_cur);
        build_kernel<<<2048, 256, 0, stream>>>(uidx, iidx, w, udeg, ideg,
                                               u_cur, i_cur, u_edges, i_edges);
        gather_kernel<<<(NUSERS * 16 + 255) / 256, 256, 0, stream>>>(
            u_edges, u_off, udeg, i_emb, out_u, NUSERS);
        gather_kernel<<<(NITEMS * 16 + 255) / 256, 256, 0, stream>>>(
            i_edges, i_off, ideg, u_emb, out_i, NITEMS);
    } else {
        // Fallback: atomic scatter (round-1 path).
        float* udeg = (float*)d_ws;
        float* ideg = udeg + NUSERS;
        hipMemsetAsync(d_ws, 0, (size_t)(NUSERS + NITEMS) * sizeof(float), stream);
        hipMemsetAsync(d_out, 0, (size_t)out_size * sizeof(float), stream);
        fb_degree_kernel<<<2048, 256, 0, stream>>>(uidx, iidx, udeg, ideg);
        long long total_threads = (long long)NEDGES * 16;
        fb_scatter_kernel<<<(int)((total_threads + 255) / 256), 256, 0, stream>>>(
            u_emb, i_emb, uidx, iidx, w, udeg, ideg, out_u, out_i);
    }
}